// Round 1
// baseline (603.500 us; speedup 1.0000x reference)
//
#include <hip/hip_runtime.h>
#include <math.h>

// Problem constants
#define B_   64
#define S_   64
#define W_   12
#define V_   32000
#define SYM_ 128
#define HID_ 256
#define E_   64
#define R_   32

// ---------------------------------------------------------------------------
// K1: sentence / query embedding sums
// sent[b,s,e] = sum_w we[story[b,s,w],e] * pe[w,e]
// ---------------------------------------------------------------------------
__global__ __launch_bounds__(128) void k_embed(
    const int* __restrict__ story, const int* __restrict__ query,
    const float* __restrict__ we, const float* __restrict__ pe,
    float* __restrict__ sent, float* __restrict__ qsum) {
  int blk = blockIdx.x;
  int e = threadIdx.x;
  if (blk < B_ * S_) {
    const int* idx = story + blk * W_;
    float acc = 0.f;
#pragma unroll
    for (int w = 0; w < W_; ++w)
      acc = fmaf(we[(long)idx[w] * SYM_ + e], pe[w * SYM_ + e], acc);
    sent[blk * SYM_ + e] = acc;
  } else {
    int b = blk - B_ * S_;
    const int* idx = query + b * W_;
    float acc = 0.f;
#pragma unroll
    for (int w = 0; w < W_; ++w)
      acc = fmaf(we[(long)idx[w] * SYM_ + e], pe[w * SYM_ + e], acc);
    qsum[b * SYM_ + e] = acc;
  }
}

// ---------------------------------------------------------------------------
// K2: two-layer MLP heads. grid = ntiles*5 blocks; h = blockIdx%5:
//   h 0,1 -> entity heads (out 64), h 2,3,4 -> role heads (out 32)
// Each block: 64 rows x full head. 4 passes of 64 hidden cols.
// X tile transposed in LDS; W1/W2 streamed from global (L1-resident).
// ---------------------------------------------------------------------------
__global__ __launch_bounds__(256) void k_mlp(
    const float* __restrict__ X,
    const float* __restrict__ eW1, const float* __restrict__ eb1,
    const float* __restrict__ eW2, const float* __restrict__ eb2,
    const float* __restrict__ rW1, const float* __restrict__ rb1,
    const float* __restrict__ rW2, const float* __restrict__ rb2,
    float* __restrict__ oE0, float* __restrict__ oE1,
    float* __restrict__ oR0, float* __restrict__ oR1, float* __restrict__ oR2) {
  __shared__ float XT[128 * 68];  // [k][row], pad 4 for banks/alignment
  __shared__ float HT[64 * 68];   // [c][row]

  int h = blockIdx.x % 5;
  int tile = blockIdx.x / 5;
  int rowbase = tile * 64;
  bool isE = (h < 2);
  const float* W1 = isE ? eW1 + h * (SYM_ * HID_) : rW1 + (h - 2) * (SYM_ * HID_);
  const float* b1 = isE ? eb1 + h * HID_ : rb1 + (h - 2) * HID_;
  const float* W2 = isE ? eW2 + h * (HID_ * E_) : rW2 + (h - 2) * (HID_ * R_);
  const float* b2 = isE ? eb2 + h * E_ : rb2 + (h - 2) * R_;
  float* out = (h == 0) ? oE0 : (h == 1) ? oE1 : (h == 2) ? oR0 : (h == 3) ? oR1 : oR2;

  int tid = threadIdx.x;
  // stage X tile transposed
  for (int i = tid; i < 64 * 128; i += 256) {
    int row = i >> 7, k = i & 127;
    XT[k * 68 + row] = X[(long)(rowbase + row) * SYM_ + k];
  }
  __syncthreads();

  int tr = tid >> 4, tc = tid & 15;
  float accE[4][4] = {};
  float accR[4][2] = {};

  for (int p = 0; p < 4; ++p) {
    int cbase = p * 64;
    float4 b1v = *(const float4*)(b1 + cbase + 4 * tc);
    float a[4][4] = {};
#pragma unroll 4
    for (int k = 0; k < 128; ++k) {
      float4 xa = *(const float4*)&XT[k * 68 + 4 * tr];
      float4 wb = *(const float4*)(W1 + k * HID_ + cbase + 4 * tc);
      float xs[4] = {xa.x, xa.y, xa.z, xa.w};
      float wsv[4] = {wb.x, wb.y, wb.z, wb.w};
#pragma unroll
      for (int i = 0; i < 4; ++i)
#pragma unroll
        for (int j = 0; j < 4; ++j) a[i][j] = fmaf(xs[i], wsv[j], a[i][j]);
    }
    __syncthreads();  // previous pass layer2 done with HT
    float b1s[4] = {b1v.x, b1v.y, b1v.z, b1v.w};
#pragma unroll
    for (int i = 0; i < 4; ++i)
#pragma unroll
      for (int j = 0; j < 4; ++j)
        HT[(4 * tc + j) * 68 + 4 * tr + i] = tanhf(a[i][j] + b1s[j]);
    __syncthreads();
    if (isE) {
#pragma unroll 2
      for (int c = 0; c < 64; ++c) {
        float4 h4 = *(const float4*)&HT[c * 68 + 4 * tr];
        float4 w4 = *(const float4*)(W2 + (long)(cbase + c) * E_ + 4 * tc);
        float hs[4] = {h4.x, h4.y, h4.z, h4.w};
        float wv[4] = {w4.x, w4.y, w4.z, w4.w};
#pragma unroll
        for (int i = 0; i < 4; ++i)
#pragma unroll
          for (int j = 0; j < 4; ++j) accE[i][j] = fmaf(hs[i], wv[j], accE[i][j]);
      }
    } else {
#pragma unroll 2
      for (int c = 0; c < 64; ++c) {
        float4 h4 = *(const float4*)&HT[c * 68 + 4 * tr];
        float2 w2 = *(const float2*)(W2 + (long)(cbase + c) * R_ + 2 * tc);
        float hs[4] = {h4.x, h4.y, h4.z, h4.w};
#pragma unroll
        for (int i = 0; i < 4; ++i) {
          accR[i][0] = fmaf(hs[i], w2.x, accR[i][0]);
          accR[i][1] = fmaf(hs[i], w2.y, accR[i][1]);
        }
      }
    }
  }
  if (isE) {
    float4 b2v = *(const float4*)(b2 + 4 * tc);
#pragma unroll
    for (int i = 0; i < 4; ++i) {
      float4 o4 = make_float4(accE[i][0] + b2v.x, accE[i][1] + b2v.y,
                              accE[i][2] + b2v.z, accE[i][3] + b2v.w);
      *(float4*)(out + (long)(rowbase + 4 * tr + i) * E_ + 4 * tc) = o4;
    }
  } else {
    float2 b2v = *(const float2*)(b2 + 2 * tc);
#pragma unroll
    for (int i = 0; i < 4; ++i) {
      float2 o2 = make_float2(accR[i][0] + b2v.x, accR[i][1] + b2v.y);
      *(float2*)(out + (long)(rowbase + 4 * tr + i) * R_ + 2 * tc) = o2;
    }
  }
}

// ---------------------------------------------------------------------------
// K3: the TPR scan. One wave per (b,f) slice; state TPR[e,r] (2048 fp32) in
// VGPRs: lane = 2r+h holds e in [32h,32h+32). Per step:
//   t1[r]  = sum_e e1[e] T[e,r]           (pair-combine over h)
//   w_hat  = sum_r r1[r] t1[r]            (5-level butterfly, lanes mod 2)
//   m_hat  = sum_r r2[r] t1[r]
//   b_hat  = sum_{e,r} e2[e] r3[r] T
//   U[r] = r1(e2f-w) + r2(w-m);  V[r] = r3(e1f-b)
//   T[e,r] += e1[e]*U + e2[e]*V
// ---------------------------------------------------------------------------
__global__ __launch_bounds__(64, 4) void k_scan(
    const float* __restrict__ e1g, const float* __restrict__ e2g,
    const float* __restrict__ r1g, const float* __restrict__ r2g,
    const float* __restrict__ r3g, float* __restrict__ tpr) {
  int b = blockIdx.x >> 6;
  int f = blockIdx.x & 63;
  int lane = threadIdx.x;
  int r = lane >> 1;
  int eb = (lane & 1) * 32;

  float T[32];
#pragma unroll
  for (int m = 0; m < 32; ++m) T[m] = 0.f;

  const float* e1b = e1g + (long)b * S_ * E_;
  const float* e2b = e2g + (long)b * S_ * E_;
  const float* r1b = r1g + (long)b * S_ * R_;
  const float* r2b = r2g + (long)b * S_ * R_;
  const float* r3b = r3g + (long)b * S_ * R_;

  for (int s = 0; s < S_; ++s) {
    const float4* E1 = (const float4*)(e1b + s * E_ + eb);
    const float4* E2 = (const float4*)(e2b + s * E_ + eb);
    float A[32], Bv[32];
#pragma unroll
    for (int j = 0; j < 8; ++j) {
      float4 a4 = E1[j];
      A[4 * j] = a4.x; A[4 * j + 1] = a4.y; A[4 * j + 2] = a4.z; A[4 * j + 3] = a4.w;
      float4 b4 = E2[j];
      Bv[4 * j] = b4.x; Bv[4 * j + 1] = b4.y; Bv[4 * j + 2] = b4.z; Bv[4 * j + 3] = b4.w;
    }
    float r1s = r1b[s * R_ + r];
    float r2s = r2b[s * R_ + r];
    float r3s = r3b[s * R_ + r];
    float e1f = e1b[s * E_ + f];
    float e2f = e2b[s * E_ + f];

    float tp[4] = {0.f, 0.f, 0.f, 0.f};
    float bq[4] = {0.f, 0.f, 0.f, 0.f};
#pragma unroll
    for (int m = 0; m < 32; ++m) {
      tp[m & 3] = fmaf(A[m], T[m], tp[m & 3]);
      bq[m & 3] = fmaf(Bv[m], T[m], bq[m & 3]);
    }
    float t1p = (tp[0] + tp[1]) + (tp[2] + tp[3]);
    float bp = (bq[0] + bq[1]) + (bq[2] + bq[3]);
    // combine the two e-halves (lanes 2r / 2r+1)
    float t1 = t1p + __shfl_xor(t1p, 1, 64);
    float bfull = bp + __shfl_xor(bp, 1, 64);
    float wh = r1s * t1;
    float mh = r2s * t1;
    float bh = r3s * bfull;
    // butterfly over masks 2..32: sums the 32 distinct r's (lanes same parity)
#pragma unroll
    for (int m = 2; m <= 32; m <<= 1) {
      wh += __shfl_xor(wh, m, 64);
      mh += __shfl_xor(mh, m, 64);
      bh += __shfl_xor(bh, m, 64);
    }
    float U = fmaf(r1s, e2f - wh, r2s * (wh - mh));
    float Vv = r3s * (e1f - bh);
#pragma unroll
    for (int m = 0; m < 32; ++m)
      T[m] = fmaf(A[m], U, fmaf(Bv[m], Vv, T[m]));
  }
  // store tpr[b][f][r][e]
  float* o = tpr + (((long)(b * 64 + f) * 32 + r) * 64 + eb);
#pragma unroll
  for (int j = 0; j < 8; ++j)
    ((float4*)o)[j] = make_float4(T[4 * j], T[4 * j + 1], T[4 * j + 2], T[4 * j + 3]);
}

// ---------------------------------------------------------------------------
// K4: inference i1->i2->i3 with LayerNorm; one block per b.
// thread = (f = tid>>2, q = tid&3), q covers 8 r's.
// ---------------------------------------------------------------------------
__global__ __launch_bounds__(256) void k_infer(
    const float* __restrict__ tpr, const float* __restrict__ qe1,
    const float* __restrict__ qr1, const float* __restrict__ qr2,
    const float* __restrict__ qr3, const float* __restrict__ lng,
    const float* __restrict__ lnb, float* __restrict__ isum) {
  int b = blockIdx.x, tid = threadIdx.x;
  __shared__ float cvec[64];
  __shared__ float part[256];
  int f = tid >> 2, q = tid & 3;
  if (tid < 64) cvec[tid] = qe1[b * 64 + tid];
  __syncthreads();
  float isacc = 0.f;
  for (int p = 0; p < 3; ++p) {
    const float* qr = ((p == 0) ? qr1 : (p == 1) ? qr2 : qr3) + b * R_;
    const float* tb = tpr + (((long)(b * 64 + f) * 32) + 8 * q) * 64;
    const float4* cv4 = (const float4*)cvec;
    float partial = 0.f;
#pragma unroll 2
    for (int rr = 0; rr < 8; ++rr) {
      const float4* row4 = (const float4*)(tb + rr * 64);
      float d0 = 0.f, d1 = 0.f, d2 = 0.f, d3 = 0.f;
#pragma unroll
      for (int jj = 0; jj < 16; ++jj) {
        float4 t4 = row4[jj];
        float4 c4 = cv4[jj];
        d0 = fmaf(t4.x, c4.x, d0);
        d1 = fmaf(t4.y, c4.y, d1);
        d2 = fmaf(t4.z, c4.z, d2);
        d3 = fmaf(t4.w, c4.w, d3);
      }
      partial = fmaf(qr[8 * q + rr], (d0 + d1) + (d2 + d3), partial);
    }
    part[tid] = partial;
    __syncthreads();
    if (tid < 64) {
      float v = (part[tid * 4 + 0] + part[tid * 4 + 1]) +
                (part[tid * 4 + 2] + part[tid * 4 + 3]);
      float mu = v;
#pragma unroll
      for (int m = 1; m <= 32; m <<= 1) mu += __shfl_xor(mu, m, 64);
      mu *= (1.f / 64.f);
      float d = v - mu;
      float vr = d * d;
#pragma unroll
      for (int m = 1; m <= 32; m <<= 1) vr += __shfl_xor(vr, m, 64);
      vr *= (1.f / 64.f);
      float iv = d * (1.f / sqrtf(vr + 1e-5f)) * lng[p * 64 + tid] + lnb[p * 64 + tid];
      cvec[tid] = iv;  // entity vector for next pass
      isacc += iv;
    }
    __syncthreads();
  }
  if (tid < 64) isum[b * 64 + tid] = isacc;
}

// ---------------------------------------------------------------------------
// K5: out[b,v] = sum_e isum[b,e] * Z[e,v].  block tile 64b x 64v, 4x4/thread.
// ---------------------------------------------------------------------------
__global__ __launch_bounds__(256) void k_final(
    const float* __restrict__ isum, const float* __restrict__ Zm,
    float* __restrict__ out) {
  __shared__ float isT[64 * 68];  // [e][b]
  int tid = threadIdx.x;
  for (int i = tid; i < 4096; i += 256) {
    int bb = i >> 6, e = i & 63;
    isT[e * 68 + bb] = isum[i];
  }
  __syncthreads();
  int tr = tid >> 4, tc = tid & 15;
  int v0 = blockIdx.x * 64 + tc * 4;
  float acc[4][4] = {};
#pragma unroll 2
  for (int e = 0; e < 64; ++e) {
    float4 a4 = *(const float4*)&isT[e * 68 + 4 * tr];
    float4 z4 = *(const float4*)(Zm + (long)e * V_ + v0);
    float as[4] = {a4.x, a4.y, a4.z, a4.w};
    float zs[4] = {z4.x, z4.y, z4.z, z4.w};
#pragma unroll
    for (int i = 0; i < 4; ++i)
#pragma unroll
      for (int j = 0; j < 4; ++j) acc[i][j] = fmaf(as[i], zs[j], acc[i][j]);
  }
#pragma unroll
  for (int i = 0; i < 4; ++i) {
    float4 o4 = make_float4(acc[i][0], acc[i][1], acc[i][2], acc[i][3]);
    *(float4*)(out + (long)(4 * tr + i) * V_ + v0) = o4;
  }
}

// ---------------------------------------------------------------------------
extern "C" void kernel_launch(void* const* d_in, const int* in_sizes, int n_in,
                              void* d_out, int out_size, void* d_ws, size_t ws_size,
                              hipStream_t stream) {
  const int* story = (const int*)d_in[0];
  const int* query = (const int*)d_in[1];
  const float* we = (const float*)d_in[2];
  const float* pe = (const float*)d_in[3];
  const float* ueW1 = (const float*)d_in[4];
  const float* ueb1 = (const float*)d_in[5];
  const float* ueW2 = (const float*)d_in[6];
  const float* ueb2 = (const float*)d_in[7];
  const float* urW1 = (const float*)d_in[8];
  const float* urb1 = (const float*)d_in[9];
  const float* urW2 = (const float*)d_in[10];
  const float* urb2 = (const float*)d_in[11];
  const float* ieW1 = (const float*)d_in[12];
  const float* ieb1 = (const float*)d_in[13];
  const float* ieW2 = (const float*)d_in[14];
  const float* ieb2 = (const float*)d_in[15];
  const float* irW1 = (const float*)d_in[16];
  const float* irb1 = (const float*)d_in[17];
  const float* irW2 = (const float*)d_in[18];
  const float* irb2 = (const float*)d_in[19];
  const float* lng = (const float*)d_in[20];
  const float* lnb = (const float*)d_in[21];
  const float* Zm = (const float*)d_in[22];

  float* ws = (float*)d_ws;
  float* sent = ws;                 // 4096*128      = 524288
  float* qsum = sent + 524288;      // 64*128        = 8192
  float* e1 = qsum + 8192;          // 4096*64       = 262144
  float* e2 = e1 + 262144;
  float* r1 = e2 + 262144;          // 4096*32       = 131072
  float* r2 = r1 + 131072;
  float* r3 = r2 + 131072;
  float* qe1 = r3 + 131072;         // 64*64         = 4096
  float* qe2s = qe1 + 4096;         // scratch (unused ie head 1)
  float* qr1 = qe2s + 4096;         // 64*32         = 2048
  float* qr2 = qr1 + 2048;
  float* qr3 = qr2 + 2048;
  float* isum = qr3 + 2048;         // 64*64         = 4096
  float* tpr = isum + 4096;         // 64*64*32*64   = 8388608
  float* outF = (float*)d_out;

  k_embed<<<B_ * S_ + B_, 128, 0, stream>>>(story, query, we, pe, sent, qsum);
  k_mlp<<<64 * 5, 256, 0, stream>>>(sent, ueW1, ueb1, ueW2, ueb2,
                                    urW1, urb1, urW2, urb2, e1, e2, r1, r2, r3);
  k_mlp<<<5, 256, 0, stream>>>(qsum, ieW1, ieb1, ieW2, ieb2,
                               irW1, irb1, irW2, irb2, qe1, qe2s, qr1, qr2, qr3);
  k_scan<<<B_ * 64, 64, 0, stream>>>(e1, e2, r1, r2, r3, tpr);
  k_infer<<<B_, 256, 0, stream>>>(tpr, qe1, qr1, qr2, qr3, lng, lnb, isum);
  k_final<<<V_ / 64, 256, 0, stream>>>(isum, Zm, outF);
}

// Round 2
// 514.912 us; speedup vs baseline: 1.1720x; 1.1720x over previous
//
#include <hip/hip_runtime.h>
#include <math.h>

// Problem constants
#define B_   64
#define S_   64
#define W_   12
#define V_   32000
#define SYM_ 128
#define HID_ 256
#define E_   64
#define R_   32

// ---------------------------------------------------------------------------
// K1: sentence / query embedding sums
// ---------------------------------------------------------------------------
__global__ __launch_bounds__(128) void k_embed(
    const int* __restrict__ story, const int* __restrict__ query,
    const float* __restrict__ we, const float* __restrict__ pe,
    float* __restrict__ sent, float* __restrict__ qsum) {
  int blk = blockIdx.x;
  int e = threadIdx.x;
  if (blk < B_ * S_) {
    const int* idx = story + blk * W_;
    float acc = 0.f;
#pragma unroll
    for (int w = 0; w < W_; ++w)
      acc = fmaf(we[(long)idx[w] * SYM_ + e], pe[w * SYM_ + e], acc);
    sent[blk * SYM_ + e] = acc;
  } else {
    int b = blk - B_ * S_;
    const int* idx = query + b * W_;
    float acc = 0.f;
#pragma unroll
    for (int w = 0; w < W_; ++w)
      acc = fmaf(we[(long)idx[w] * SYM_ + e], pe[w * SYM_ + e], acc);
    qsum[b * SYM_ + e] = acc;
  }
}

// ---------------------------------------------------------------------------
// K2: two-layer MLP heads (unchanged from R1 — ~15 us, not the bottleneck)
// ---------------------------------------------------------------------------
__global__ __launch_bounds__(256) void k_mlp(
    const float* __restrict__ X,
    const float* __restrict__ eW1, const float* __restrict__ eb1,
    const float* __restrict__ eW2, const float* __restrict__ eb2,
    const float* __restrict__ rW1, const float* __restrict__ rb1,
    const float* __restrict__ rW2, const float* __restrict__ rb2,
    float* __restrict__ oE0, float* __restrict__ oE1,
    float* __restrict__ oR0, float* __restrict__ oR1, float* __restrict__ oR2) {
  __shared__ float XT[128 * 68];
  __shared__ float HT[64 * 68];

  int h = blockIdx.x % 5;
  int tile = blockIdx.x / 5;
  int rowbase = tile * 64;
  bool isE = (h < 2);
  const float* W1 = isE ? eW1 + h * (SYM_ * HID_) : rW1 + (h - 2) * (SYM_ * HID_);
  const float* b1 = isE ? eb1 + h * HID_ : rb1 + (h - 2) * HID_;
  const float* W2 = isE ? eW2 + h * (HID_ * E_) : rW2 + (h - 2) * (HID_ * R_);
  const float* b2 = isE ? eb2 + h * E_ : rb2 + (h - 2) * R_;
  float* out = (h == 0) ? oE0 : (h == 1) ? oE1 : (h == 2) ? oR0 : (h == 3) ? oR1 : oR2;

  int tid = threadIdx.x;
  for (int i = tid; i < 64 * 128; i += 256) {
    int row = i >> 7, k = i & 127;
    XT[k * 68 + row] = X[(long)(rowbase + row) * SYM_ + k];
  }
  __syncthreads();

  int tr = tid >> 4, tc = tid & 15;
  float accE[4][4] = {};
  float accR[4][2] = {};

  for (int p = 0; p < 4; ++p) {
    int cbase = p * 64;
    float4 b1v = *(const float4*)(b1 + cbase + 4 * tc);
    float a[4][4] = {};
#pragma unroll 4
    for (int k = 0; k < 128; ++k) {
      float4 xa = *(const float4*)&XT[k * 68 + 4 * tr];
      float4 wb = *(const float4*)(W1 + k * HID_ + cbase + 4 * tc);
      float xs[4] = {xa.x, xa.y, xa.z, xa.w};
      float wsv[4] = {wb.x, wb.y, wb.z, wb.w};
#pragma unroll
      for (int i = 0; i < 4; ++i)
#pragma unroll
        for (int j = 0; j < 4; ++j) a[i][j] = fmaf(xs[i], wsv[j], a[i][j]);
    }
    __syncthreads();
    float b1s[4] = {b1v.x, b1v.y, b1v.z, b1v.w};
#pragma unroll
    for (int i = 0; i < 4; ++i)
#pragma unroll
      for (int j = 0; j < 4; ++j)
        HT[(4 * tc + j) * 68 + 4 * tr + i] = tanhf(a[i][j] + b1s[j]);
    __syncthreads();
    if (isE) {
#pragma unroll 2
      for (int c = 0; c < 64; ++c) {
        float4 h4 = *(const float4*)&HT[c * 68 + 4 * tr];
        float4 w4 = *(const float4*)(W2 + (long)(cbase + c) * E_ + 4 * tc);
        float hs[4] = {h4.x, h4.y, h4.z, h4.w};
        float wv[4] = {w4.x, w4.y, w4.z, w4.w};
#pragma unroll
        for (int i = 0; i < 4; ++i)
#pragma unroll
          for (int j = 0; j < 4; ++j) accE[i][j] = fmaf(hs[i], wv[j], accE[i][j]);
      }
    } else {
#pragma unroll 2
      for (int c = 0; c < 64; ++c) {
        float4 h4 = *(const float4*)&HT[c * 68 + 4 * tr];
        float2 w2 = *(const float2*)(W2 + (long)(cbase + c) * R_ + 2 * tc);
        float hs[4] = {h4.x, h4.y, h4.z, h4.w};
#pragma unroll
        for (int i = 0; i < 4; ++i) {
          accR[i][0] = fmaf(hs[i], w2.x, accR[i][0]);
          accR[i][1] = fmaf(hs[i], w2.y, accR[i][1]);
        }
      }
    }
  }
  if (isE) {
    float4 b2v = *(const float4*)(b2 + 4 * tc);
#pragma unroll
    for (int i = 0; i < 4; ++i) {
      float4 o4 = make_float4(accE[i][0] + b2v.x, accE[i][1] + b2v.y,
                              accE[i][2] + b2v.z, accE[i][3] + b2v.w);
      *(float4*)(out + (long)(rowbase + 4 * tr + i) * E_ + 4 * tc) = o4;
    }
  } else {
    float2 b2v = *(const float2*)(b2 + 2 * tc);
#pragma unroll
    for (int i = 0; i < 4; ++i) {
      float2 o2 = make_float2(accR[i][0] + b2v.x, accR[i][1] + b2v.y);
      *(float2*)(out + (long)(rowbase + 4 * tr + i) * R_ + 2 * tc) = o2;
    }
  }
}

// ---------------------------------------------------------------------------
// K3: TPR scan, lane = (f-half, r) layout.
// Wave w of batch b handles f in {2w, 2w+1}. Lane = 32*h + r, h selects f.
// Per-lane state: T[e=0..63] for its (r, f) — 64 VGPRs.
// e1/e2 step vectors are WAVE-UNIFORM -> scalar (SGPR) loads; every FMA is
// v_fma_f32 v,s,v. Reductions over r via 5-level butterfly within each half.
// ---------------------------------------------------------------------------
__global__ __launch_bounds__(64) void k_scan(
    const float* __restrict__ e1g, const float* __restrict__ e2g,
    const float* __restrict__ r1g, const float* __restrict__ r2g,
    const float* __restrict__ r3g, float* __restrict__ tpr) {
  int b = blockIdx.x >> 5;      // 32 waves per batch
  int w = blockIdx.x & 31;
  int lane = threadIdx.x;
  int h = lane >> 5;            // which of the wave's 2 f-slices
  int r = lane & 31;
  int f = 2 * w + h;

  float T[64];
#pragma unroll
  for (int e = 0; e < 64; ++e) T[e] = 0.f;

  const float* e1b = e1g + (long)b * S_ * E_;
  const float* e2b = e2g + (long)b * S_ * E_;
  const float* r1b = r1g + (long)b * S_ * R_;
  const float* r2b = r2g + (long)b * S_ * R_;
  const float* r3b = r3g + (long)b * S_ * R_;

  for (int s = 0; s < S_; ++s) {
    // wave-uniform pointers -> compiler scalarizes to s_load (SGPR data)
    const float* sa = e1b + s * E_;
    const float* sb = e2b + s * E_;
    // per-lane loads (VMEM, small, L1-resident)
    float r1s = r1b[s * R_ + r];
    float r2s = r2b[s * R_ + r];
    float r3s = r3b[s * R_ + r];
    float e1f = e1b[s * E_ + f];
    float e2f = e2b[s * E_ + f];

    // t1 = sum_e e1[e] T[e] ; bq = sum_e e2[e] T[e]  (4 accumulators each)
    float tp[4] = {0.f, 0.f, 0.f, 0.f};
    float bp[4] = {0.f, 0.f, 0.f, 0.f};
#pragma unroll
    for (int e = 0; e < 64; ++e) {
      float a = sa[e], c = sb[e];
      tp[e & 3] = fmaf(a, T[e], tp[e & 3]);
      bp[e & 3] = fmaf(c, T[e], bp[e & 3]);
    }
    float t1 = (tp[0] + tp[1]) + (tp[2] + tp[3]);
    float bq = (bp[0] + bp[1]) + (bp[2] + bp[3]);

    float wh = r1s * t1;
    float mh = r2s * t1;
    float bh = r3s * bq;
    // butterfly over 32 r's (masks 1..16 stay within the 32-lane half)
#pragma unroll
    for (int m = 1; m <= 16; m <<= 1) {
      wh += __shfl_xor(wh, m, 64);
      mh += __shfl_xor(mh, m, 64);
      bh += __shfl_xor(bh, m, 64);
    }
    float U = fmaf(r1s, e2f - wh, r2s * (wh - mh));
    float Vv = r3s * (e1f - bh);
#pragma unroll
    for (int e = 0; e < 64; ++e)
      T[e] = fmaf(sa[e], U, fmaf(sb[e], Vv, T[e]));
  }
  // store tpr[b][f][r][e]
  float* o = tpr + (((long)(b * 64 + f) * 32 + r) * 64);
#pragma unroll
  for (int j = 0; j < 16; ++j)
    ((float4*)o)[j] = make_float4(T[4 * j], T[4 * j + 1], T[4 * j + 2], T[4 * j + 3]);
}

// ---------------------------------------------------------------------------
// K4: inference i1->i2->i3 with LayerNorm; one block of 1024 per b.
// thread = (f = tid>>4, j = tid&15) covering r = j and r = j+16.
// ---------------------------------------------------------------------------
__global__ __launch_bounds__(1024) void k_infer(
    const float* __restrict__ tpr, const float* __restrict__ qe1,
    const float* __restrict__ qr1, const float* __restrict__ qr2,
    const float* __restrict__ qr3, const float* __restrict__ lng,
    const float* __restrict__ lnb, float* __restrict__ isum) {
  int b = blockIdx.x, tid = threadIdx.x;
  __shared__ float cvec[64];
  __shared__ float dots[64];
  int f = tid >> 4, j = tid & 15;
  if (tid < 64) cvec[tid] = qe1[b * 64 + tid];
  __syncthreads();
  float isacc = 0.f;
  for (int p = 0; p < 3; ++p) {
    const float* qr = ((p == 0) ? qr1 : (p == 1) ? qr2 : qr3) + b * R_;
    const float4* cv4 = (const float4*)cvec;
    const float* tb = tpr + ((long)(b * 64 + f) * 32) * 64;
    float partial = 0.f;
#pragma unroll
    for (int half = 0; half < 2; ++half) {
      int rr = j + 16 * half;
      const float4* row4 = (const float4*)(tb + rr * 64);
      float d0 = 0.f, d1 = 0.f, d2 = 0.f, d3 = 0.f;
#pragma unroll
      for (int jj = 0; jj < 16; ++jj) {
        float4 t4 = row4[jj];
        float4 c4 = cv4[jj];
        d0 = fmaf(t4.x, c4.x, d0);
        d1 = fmaf(t4.y, c4.y, d1);
        d2 = fmaf(t4.z, c4.z, d2);
        d3 = fmaf(t4.w, c4.w, d3);
      }
      partial = fmaf(qr[rr], (d0 + d1) + (d2 + d3), partial);
    }
    // reduce over the 16 threads sharing this f (masks 1..8 stay in-group)
#pragma unroll
    for (int m = 1; m <= 8; m <<= 1) partial += __shfl_xor(partial, m, 64);
    if (j == 0) dots[f] = partial;
    __syncthreads();
    if (tid < 64) {
      float v = dots[tid];
      float mu = v;
#pragma unroll
      for (int m = 1; m <= 32; m <<= 1) mu += __shfl_xor(mu, m, 64);
      mu *= (1.f / 64.f);
      float d = v - mu;
      float vr = d * d;
#pragma unroll
      for (int m = 1; m <= 32; m <<= 1) vr += __shfl_xor(vr, m, 64);
      vr *= (1.f / 64.f);
      float iv = d * (1.f / sqrtf(vr + 1e-5f)) * lng[p * 64 + tid] + lnb[p * 64 + tid];
      cvec[tid] = iv;
      isacc += iv;
    }
    __syncthreads();
  }
  if (tid < 64) isum[b * 64 + tid] = isacc;
}

// ---------------------------------------------------------------------------
// K5: out[b,v] = sum_e isum[b,e] * Z[e,v]
// ---------------------------------------------------------------------------
__global__ __launch_bounds__(256) void k_final(
    const float* __restrict__ isum, const float* __restrict__ Zm,
    float* __restrict__ out) {
  __shared__ float isT[64 * 68];
  int tid = threadIdx.x;
  for (int i = tid; i < 4096; i += 256) {
    int bb = i >> 6, e = i & 63;
    isT[e * 68 + bb] = isum[i];
  }
  __syncthreads();
  int tr = tid >> 4, tc = tid & 15;
  int v0 = blockIdx.x * 64 + tc * 4;
  float acc[4][4] = {};
#pragma unroll 2
  for (int e = 0; e < 64; ++e) {
    float4 a4 = *(const float4*)&isT[e * 68 + 4 * tr];
    float4 z4 = *(const float4*)(Zm + (long)e * V_ + v0);
    float as[4] = {a4.x, a4.y, a4.z, a4.w};
    float zs[4] = {z4.x, z4.y, z4.z, z4.w};
#pragma unroll
    for (int i = 0; i < 4; ++i)
#pragma unroll
      for (int j = 0; j < 4; ++j) acc[i][j] = fmaf(as[i], zs[j], acc[i][j]);
  }
#pragma unroll
  for (int i = 0; i < 4; ++i) {
    float4 o4 = make_float4(acc[i][0], acc[i][1], acc[i][2], acc[i][3]);
    *(float4*)(out + (long)(4 * tr + i) * V_ + v0) = o4;
  }
}

// ---------------------------------------------------------------------------
extern "C" void kernel_launch(void* const* d_in, const int* in_sizes, int n_in,
                              void* d_out, int out_size, void* d_ws, size_t ws_size,
                              hipStream_t stream) {
  const int* story = (const int*)d_in[0];
  const int* query = (const int*)d_in[1];
  const float* we = (const float*)d_in[2];
  const float* pe = (const float*)d_in[3];
  const float* ueW1 = (const float*)d_in[4];
  const float* ueb1 = (const float*)d_in[5];
  const float* ueW2 = (const float*)d_in[6];
  const float* ueb2 = (const float*)d_in[7];
  const float* urW1 = (const float*)d_in[8];
  const float* urb1 = (const float*)d_in[9];
  const float* urW2 = (const float*)d_in[10];
  const float* urb2 = (const float*)d_in[11];
  const float* ieW1 = (const float*)d_in[12];
  const float* ieb1 = (const float*)d_in[13];
  const float* ieW2 = (const float*)d_in[14];
  const float* ieb2 = (const float*)d_in[15];
  const float* irW1 = (const float*)d_in[16];
  const float* irb1 = (const float*)d_in[17];
  const float* irW2 = (const float*)d_in[18];
  const float* irb2 = (const float*)d_in[19];
  const float* lng = (const float*)d_in[20];
  const float* lnb = (const float*)d_in[21];
  const float* Zm = (const float*)d_in[22];

  float* ws = (float*)d_ws;
  float* sent = ws;                 // 4096*128
  float* qsum = sent + 524288;      // 64*128
  float* e1 = qsum + 8192;          // 4096*64
  float* e2 = e1 + 262144;
  float* r1 = e2 + 262144;          // 4096*32
  float* r2 = r1 + 131072;
  float* r3 = r2 + 131072;
  float* qe1 = r3 + 131072;         // 64*64
  float* qe2s = qe1 + 4096;         // scratch (unused ie head 1)
  float* qr1 = qe2s + 4096;         // 64*32
  float* qr2 = qr1 + 2048;
  float* qr3 = qr2 + 2048;
  float* isum = qr3 + 2048;         // 64*64
  float* tpr = isum + 4096;         // 64*64*32*64 = 8388608
  float* outF = (float*)d_out;

  k_embed<<<B_ * S_ + B_, 128, 0, stream>>>(story, query, we, pe, sent, qsum);
  k_mlp<<<64 * 5, 256, 0, stream>>>(sent, ueW1, ueb1, ueW2, ueb2,
                                    urW1, urb1, urW2, urb2, e1, e2, r1, r2, r3);
  k_mlp<<<5, 256, 0, stream>>>(qsum, ieW1, ieb1, ieW2, ieb2,
                               irW1, irb1, irW2, irb2, qe1, qe2s, qr1, qr2, qr3);
  k_scan<<<B_ * 32, 64, 0, stream>>>(e1, e2, r1, r2, r3, tpr);
  k_infer<<<B_, 1024, 0, stream>>>(tpr, qe1, qr1, qr2, qr3, lng, lnb, isum);
  k_final<<<V_ / 64, 256, 0, stream>>>(isum, Zm, outF);
}